// Round 3
// baseline (1249.780 us; speedup 1.0000x reference)
//
#include <hip/hip_runtime.h>
#include <stdint.h>
#include <stddef.h>

#define T_TOK 1024
#define NE    16
#define TOPK  4
#define HID   2048
#define INTER 2048
#define CAP   512          // 2*T*K/E
#define GLIMIT 7.0f
#define GALPHA 1.702f
#define BKH   64           // halfs per stage-row (128 B)

typedef __attribute__((ext_vector_type(8))) _Float16 half8;
typedef __attribute__((ext_vector_type(4))) float     f32x4;

__device__ inline void gld16(const void* g, void* l) {
    __builtin_amdgcn_global_load_lds(
        (const __attribute__((address_space(1))) unsigned int*)g,
        (__attribute__((address_space(3))) unsigned int*)l, 16, 0, 0);
}

// ---------------- gating: softmax + top4 + renormalize ----------------
__global__ __launch_bounds__(256) void gating_kernel(
    const float* __restrict__ logits, int* __restrict__ topki, float* __restrict__ topkw)
{
    int t = blockIdx.x * 256 + threadIdx.x;
    if (t >= T_TOK) return;
    float l[NE];
#pragma unroll
    for (int e = 0; e < NE; e++) l[e] = logits[t * NE + e];
    unsigned used = 0;
    float val[TOPK]; int idx[TOPK];
#pragma unroll
    for (int k = 0; k < TOPK; k++) {
        float bv = -3.4e38f; int bi = 0;
#pragma unroll
        for (int e = 0; e < NE; e++) {
            bool ok = (((used >> e) & 1u) == 0u) && (l[e] > bv);
            bv = ok ? l[e] : bv;
            bi = ok ? e : bi;
        }
        used |= (1u << bi); idx[k] = bi; val[k] = bv;
    }
    float m = val[0];
    float s = 0.f, w[TOPK];
#pragma unroll
    for (int k = 0; k < TOPK; k++) { w[k] = expf(val[k] - m); s += w[k]; }
    float inv = 1.0f / s;
#pragma unroll
    for (int k = 0; k < TOPK; k++) { topki[t * TOPK + k] = idx[k]; topkw[t * TOPK + k] = w[k] * inv; }
}

// ---------------- per-token dynamic int8 quant (stored as fp16) ----------------
__global__ __launch_bounds__(256) void quant_x_kernel(
    const float* __restrict__ x, _Float16* __restrict__ xq, float* __restrict__ xs)
{
    int t = blockIdx.x;
    const float* row = x + (size_t)t * HID;
    __shared__ float red[256];
    float4 v0 = *(const float4*)(row + threadIdx.x * 8);
    float4 v1 = *(const float4*)(row + threadIdx.x * 8 + 4);
    float amax = fmaxf(fmaxf(fmaxf(fabsf(v0.x), fabsf(v0.y)), fmaxf(fabsf(v0.z), fabsf(v0.w))),
                       fmaxf(fmaxf(fabsf(v1.x), fabsf(v1.y)), fmaxf(fabsf(v1.z), fabsf(v1.w))));
    red[threadIdx.x] = amax; __syncthreads();
    for (int s = 128; s > 0; s >>= 1) {
        if (threadIdx.x < s) red[threadIdx.x] = fmaxf(red[threadIdx.x], red[threadIdx.x + s]);
        __syncthreads();
    }
    float scale = fmaxf(red[0] / 127.0f, 1e-8f);
    if (threadIdx.x == 0) xs[t] = scale;
    float inv = 1.0f / scale;
    float q[8] = {v0.x, v0.y, v0.z, v0.w, v1.x, v1.y, v1.z, v1.w};
    half8 o;
#pragma unroll
    for (int i = 0; i < 8; i++) {
        float qq = fminf(fmaxf(rintf(q[i] * inv), -127.f), 127.f);
        o[i] = (_Float16)qq;
    }
    *(half8*)(xq + (size_t)t * HID + threadIdx.x * 8) = o;
}

// ---------------- routing: order-exact positions, one wave per expert ----------------
__global__ __launch_bounds__(1024) void routing_kernel(
    const int* __restrict__ topki, const float* __restrict__ topkw,
    int* __restrict__ row_src, float* __restrict__ row_w, int* __restrict__ counts)
{
    int wv = threadIdx.x >> 6;   // expert id
    int lane = threadIdx.x & 63;
    int base = 0;
    for (int r0 = 0; r0 < T_TOK * TOPK; r0 += 64) {
        int r = r0 + lane;
        int e = topki[r];
        unsigned long long mask = __ballot(e == wv);
        int pre = __popcll(mask & ((1ULL << lane) - 1ULL));
        if (e == wv) {
            int pos = base + pre;
            if (pos < CAP) {
                row_src[wv * CAP + pos] = r >> 2;
                row_w[wv * CAP + pos] = topkw[r];
            }
        }
        base += __popcll(mask);
    }
    if (lane == 0) counts[wv] = (base < CAP) ? base : CAP;
}

// ---------------- weight prepass: f32 [K][N] -> f16 [N][K] ----------------
__global__ __launch_bounds__(256) void wtrans_kernel(
    const float* __restrict__ W, _Float16* __restrict__ Wt, int N, int K)
{
    int e = blockIdx.z;
    const float* We = W + (size_t)e * K * N;
    _Float16* Wte = Wt + (size_t)e * N * K;
    int n0 = blockIdx.x * 64, k0 = blockIdx.y * 64;
    __shared__ _Float16 sT[64][72];
    int t = threadIdx.x;
    int kr = t >> 2;
    int nb = (t & 3) * 16;
    const float* src = We + (size_t)(k0 + kr) * N + n0 + nb;
#pragma unroll
    for (int i = 0; i < 4; i++) {
        float4 v = *(const float4*)(src + i * 4);
        sT[nb + i * 4 + 0][kr] = (_Float16)v.x;
        sT[nb + i * 4 + 1][kr] = (_Float16)v.y;
        sT[nb + i * 4 + 2][kr] = (_Float16)v.z;
        sT[nb + i * 4 + 3][kr] = (_Float16)v.w;
    }
    __syncthreads();
    int nr = t >> 2, seg = t & 3;
    _Float16* dst = Wte + (size_t)(n0 + nr) * K + k0 + seg * 16;
    int4 a = *(const int4*)&sT[nr][seg * 16];
    int4 b = *(const int4*)&sT[nr][seg * 16 + 8];
    *(int4*)dst = a;
    *(int4*)(dst + 8) = b;
}

// ---------------- GEMM1: m97-style, global_load_lds staging, fused swiglu ----------------
// block 256 thr = 4 waves; tile 128 rows x (64 gate + 64 up) cols; BK=64 halfs
__global__ __launch_bounds__(256) void gemm1_kernel(
    const _Float16* __restrict__ xq, const float* __restrict__ xs,
    const int* __restrict__ row_src, const int* __restrict__ counts,
    const _Float16* __restrict__ wt1,   // [E][4096][2048] f16, [n][k]
    const float* __restrict__ gus, const float* __restrict__ gub,
    const float* __restrict__ smo, _Float16* __restrict__ act)
{
    int nt = blockIdx.x;        // 0..31
    int mt = blockIdx.y;        // 0..3
    int e  = blockIdx.z;
    int count = counts[e];
    int m0 = mt * 128;
    if (m0 >= count) return;

    __shared__ _Float16 sA[128 * BKH];
    __shared__ _Float16 sB[128 * BKH];

    int t = threadIdx.x;
    int wv = t >> 6, lane = t & 63;
    int n16 = lane & 15, quad = lane >> 4;
    int seg = lane & 7, rsub = lane >> 3;
    int swz8 = (seg ^ rsub) * 8;     // swizzled 16-B segment (halfs offset)

    const _Float16* wte = wt1 + (size_t)e * 4096 * 2048;
    const _Float16* aSrc[4];
    const _Float16* bSrc[4];
    _Float16* aDst[4];
    _Float16* bDst[4];
#pragma unroll
    for (int j = 0; j < 4; j++) {
        int rr = wv * 32 + j * 8 + rsub;      // tile row / tile col, 0..127
        int gr = m0 + rr;
        int cl = gr < count ? gr : (count - 1);
        aSrc[j] = xq + (size_t)row_src[e * CAP + cl] * HID + swz8;
        int nIdx = (rr < 64) ? (nt * 64 + rr) : (2048 + nt * 64 + (rr - 64));
        bSrc[j] = wte + (size_t)nIdx * 2048 + swz8;
        aDst[j] = &sA[(wv * 32 + j * 8) * BKH];
        bDst[j] = &sB[(wv * 32 + j * 8) * BKH];
    }

    int rhalf = (wv & 1) * 64, chalf = (wv >> 1) * 32;
    int aOff[4][2], bOff[4][2];
#pragma unroll
    for (int mf = 0; mf < 4; mf++)
#pragma unroll
        for (int ks = 0; ks < 2; ks++) {
            int row = rhalf + mf * 16 + n16;
            aOff[mf][ks] = row * BKH + (((ks * 4 + quad) ^ (row & 7)) * 8);
        }
#pragma unroll
    for (int nf = 0; nf < 4; nf++)
#pragma unroll
        for (int ks = 0; ks < 2; ks++) {
            int row = (nf < 2) ? (chalf + nf * 16 + n16) : (64 + chalf + (nf - 2) * 16 + n16);
            bOff[nf][ks] = row * BKH + (((ks * 4 + quad) ^ (row & 7)) * 8);
        }

    f32x4 acc[4][4];
#pragma unroll
    for (int i = 0; i < 4; i++)
#pragma unroll
        for (int j = 0; j < 4; j++) acc[i][j] = (f32x4)0.0f;

    for (int k0 = 0; k0 < HID; k0 += BKH) {
        __syncthreads();
#pragma unroll
        for (int j = 0; j < 4; j++) {
            gld16(aSrc[j], aDst[j]);
            gld16(bSrc[j], bDst[j]);
            aSrc[j] += BKH; bSrc[j] += BKH;
        }
        __syncthreads();
#pragma unroll
        for (int ks = 0; ks < 2; ks++) {
            half8 af[4], bf[4];
#pragma unroll
            for (int mf = 0; mf < 4; mf++) af[mf] = *(const half8*)&sA[aOff[mf][ks]];
#pragma unroll
            for (int nf = 0; nf < 4; nf++) bf[nf] = *(const half8*)&sB[bOff[nf][ks]];
#pragma unroll
            for (int mf = 0; mf < 4; mf++)
#pragma unroll
                for (int nf = 0; nf < 4; nf++)
                    acc[mf][nf] = __builtin_amdgcn_mfma_f32_16x16x32_f16(af[mf], bf[nf], acc[mf][nf], 0, 0, 0);
        }
    }

    const float* gsc = gus + (size_t)e * (2 * INTER);
    const float* gbi = gub + (size_t)e * (2 * INTER);
    const float* sms = smo + (size_t)e * INTER;
    int cg = nt * 64 + chalf;
#pragma unroll
    for (int mf = 0; mf < 4; mf++) {
#pragma unroll
        for (int r = 0; r < 4; r++) {
            int gr = m0 + rhalf + mf * 16 + quad * 4 + r;
            if (gr >= count) continue;
            float srow = xs[row_src[e * CAP + gr]];
            _Float16* arow = act + (size_t)(e * CAP + gr) * INTER;
#pragma unroll
            for (int nf = 0; nf < 2; nf++) {
                int col = cg + nf * 16 + n16;
                float yg = acc[mf][nf][r]     * srow * gsc[col]         + gbi[col];
                float yu = acc[mf][nf + 2][r] * srow * gsc[INTER + col] + gbi[INTER + col];
                float gate = fminf(yg, GLIMIT);
                float up   = fminf(fmaxf(yu, -GLIMIT), GLIMIT);
                float sig  = 1.0f / (1.0f + expf(-GALPHA * gate));
                arow[col] = (_Float16)(gate * sig * (up + 1.0f) * sms[col]);
            }
        }
    }
}

// ---------------- per-row dynamic requant of act (f16 in, f16 int8-valued out) ----------------
__global__ __launch_bounds__(256) void requant_kernel(
    const _Float16* __restrict__ act, const int* __restrict__ counts,
    _Float16* __restrict__ hq, float* __restrict__ hs)
{
    int b = blockIdx.x;           // e*CAP + c
    int e = b >> 9, c = b & (CAP - 1);
    if (c >= counts[e]) return;
    const _Float16* row = act + (size_t)b * INTER;
    __shared__ float red[256];
    half8 v = *(const half8*)(row + threadIdx.x * 8);
    float f[8];
    float amax = 0.f;
#pragma unroll
    for (int i = 0; i < 8; i++) { f[i] = (float)v[i]; amax = fmaxf(amax, fabsf(f[i])); }
    red[threadIdx.x] = amax; __syncthreads();
    for (int s = 128; s > 0; s >>= 1) {
        if (threadIdx.x < s) red[threadIdx.x] = fmaxf(red[threadIdx.x], red[threadIdx.x + s]);
        __syncthreads();
    }
    float scale = fmaxf(red[0] / 127.0f, 1e-8f);
    if (threadIdx.x == 0) hs[b] = scale;
    float inv = 1.0f / scale;
    half8 o;
#pragma unroll
    for (int i = 0; i < 8; i++) {
        float q = fminf(fmaxf(rintf(f[i] * inv), -127.f), 127.f);
        o[i] = (_Float16)q;
    }
    *(half8*)(hq + (size_t)b * INTER + threadIdx.x * 8) = o;
}

// ---------------- GEMM2: m97-style + dequant + weighted atomic combine ----------------
__global__ __launch_bounds__(256) void gemm2_kernel(
    const _Float16* __restrict__ hq, const float* __restrict__ hs,
    const int* __restrict__ row_src, const float* __restrict__ row_w,
    const int* __restrict__ counts,
    const _Float16* __restrict__ wt2,   // [E][2048][2048] f16, [n][k]
    const float* __restrict__ dsc, const float* __restrict__ dbi,
    float* __restrict__ out)
{
    int nt = blockIdx.x;        // 0..15
    int mt = blockIdx.y;        // 0..3
    int e  = blockIdx.z;
    int count = counts[e];
    int m0 = mt * 128;
    if (m0 >= count) return;

    __shared__ _Float16 sA[128 * BKH];
    __shared__ _Float16 sB[128 * BKH];

    int t = threadIdx.x;
    int wv = t >> 6, lane = t & 63;
    int n16 = lane & 15, quad = lane >> 4;
    int seg = lane & 7, rsub = lane >> 3;
    int swz8 = (seg ^ rsub) * 8;

    const _Float16* wte = wt2 + (size_t)e * 2048 * 2048;
    const _Float16* aSrc[4];
    const _Float16* bSrc[4];
    _Float16* aDst[4];
    _Float16* bDst[4];
#pragma unroll
    for (int j = 0; j < 4; j++) {
        int rr = wv * 32 + j * 8 + rsub;
        int gr = m0 + rr;
        int cl = gr < count ? gr : (count - 1);
        aSrc[j] = hq + (size_t)(e * CAP + cl) * INTER + swz8;
        bSrc[j] = wte + (size_t)(nt * 128 + rr) * 2048 + swz8;
        aDst[j] = &sA[(wv * 32 + j * 8) * BKH];
        bDst[j] = &sB[(wv * 32 + j * 8) * BKH];
    }

    int rhalf = (wv & 1) * 64, chalf = (wv >> 1) * 64;
    int aOff[4][2], bOff[4][2];
#pragma unroll
    for (int mf = 0; mf < 4; mf++)
#pragma unroll
        for (int ks = 0; ks < 2; ks++) {
            int row = rhalf + mf * 16 + n16;
            aOff[mf][ks] = row * BKH + (((ks * 4 + quad) ^ (row & 7)) * 8);
        }
#pragma unroll
    for (int nf = 0; nf < 4; nf++)
#pragma unroll
        for (int ks = 0; ks < 2; ks++) {
            int row = chalf + nf * 16 + n16;
            bOff[nf][ks] = row * BKH + (((ks * 4 + quad) ^ (row & 7)) * 8);
        }

    f32x4 acc[4][4];
#pragma unroll
    for (int i = 0; i < 4; i++)
#pragma unroll
        for (int j = 0; j < 4; j++) acc[i][j] = (f32x4)0.0f;

    for (int k0 = 0; k0 < INTER; k0 += BKH) {
        __syncthreads();
#pragma unroll
        for (int j = 0; j < 4; j++) {
            gld16(aSrc[j], aDst[j]);
            gld16(bSrc[j], bDst[j]);
            aSrc[j] += BKH; bSrc[j] += BKH;
        }
        __syncthreads();
#pragma unroll
        for (int ks = 0; ks < 2; ks++) {
            half8 af[4], bf[4];
#pragma unroll
            for (int mf = 0; mf < 4; mf++) af[mf] = *(const half8*)&sA[aOff[mf][ks]];
#pragma unroll
            for (int nf = 0; nf < 4; nf++) bf[nf] = *(const half8*)&sB[bOff[nf][ks]];
#pragma unroll
            for (int mf = 0; mf < 4; mf++)
#pragma unroll
                for (int nf = 0; nf < 4; nf++)
                    acc[mf][nf] = __builtin_amdgcn_mfma_f32_16x16x32_f16(af[mf], bf[nf], acc[mf][nf], 0, 0, 0);
        }
    }

    const float* dscE = dsc + (size_t)e * HID;
    const float* dbiE = dbi + (size_t)e * HID;
#pragma unroll
    for (int mf = 0; mf < 4; mf++) {
#pragma unroll
        for (int r = 0; r < 4; r++) {
            int gr = m0 + rhalf + mf * 16 + quad * 4 + r;
            if (gr >= count) continue;
            int ri = e * CAP + gr;
            float hsr = hs[ri];
            float wr  = row_w[ri];
            float* orow = out + (size_t)row_src[ri] * HID;
#pragma unroll
            for (int nf = 0; nf < 4; nf++) {
                int col = nt * 128 + chalf + nf * 16 + n16;
                float z = acc[mf][nf][r] * hsr * dscE[col] + dbiE[col];
                atomicAdd(&orow[col], wr * z);
            }
        }
    }
}

// ---------------- launch ----------------
extern "C" void kernel_launch(void* const* d_in, const int* in_sizes, int n_in,
                              void* d_out, int out_size, void* d_ws, size_t ws_size,
                              hipStream_t stream)
{
    (void)in_sizes; (void)n_in; (void)out_size; (void)ws_size;
    const float* x   = (const float*)d_in[0];
    const float* rl  = (const float*)d_in[1];
    const float* gup = (const float*)d_in[2];
    const float* gus = (const float*)d_in[3];
    const float* gub = (const float*)d_in[4];
    const float* smo = (const float*)d_in[5];
    const float* dwn = (const float*)d_in[6];
    const float* dsc = (const float*)d_in[7];
    const float* dbi = (const float*)d_in[8];
    float* out = (float*)d_out;

    char* p = (char*)d_ws;
    auto carve = [&](size_t bytes) -> char* {
        char* r = p; p += (bytes + 255) & ~(size_t)255; return r;
    };
    _Float16* xq   = (_Float16*)carve((size_t)T_TOK * HID * 2);
    float* xs      = (float*)carve((size_t)T_TOK * 4);
    int* topki     = (int*)carve((size_t)T_TOK * TOPK * 4);
    float* topkw   = (float*)carve((size_t)T_TOK * TOPK * 4);
    int* counts    = (int*)carve((size_t)NE * 4);
    int* rsrc      = (int*)carve((size_t)NE * CAP * 4);
    float* rw      = (float*)carve((size_t)NE * CAP * 4);
    _Float16* wt1  = (_Float16*)carve((size_t)NE * 4096 * 2048 * 2);
    _Float16* wt2  = (_Float16*)carve((size_t)NE * 2048 * 2048 * 2);
    _Float16* actb = (_Float16*)carve((size_t)NE * CAP * INTER * 2);
    _Float16* hq   = (_Float16*)carve((size_t)NE * CAP * INTER * 2);
    float* hsb     = (float*)carve((size_t)NE * CAP * 4);

    hipMemsetAsync(d_out, 0, (size_t)T_TOK * HID * 4, stream);
    gating_kernel<<<dim3((T_TOK + 255) / 256), 256, 0, stream>>>(rl, topki, topkw);
    quant_x_kernel<<<dim3(T_TOK), 256, 0, stream>>>(x, xq, xs);
    routing_kernel<<<dim3(1), 1024, 0, stream>>>(topki, topkw, rsrc, rw, counts);
    wtrans_kernel<<<dim3(64, 32, NE), 256, 0, stream>>>(gup, wt1, 2 * INTER, HID);
    wtrans_kernel<<<dim3(32, 32, NE), 256, 0, stream>>>(dwn, wt2, HID, INTER);
    gemm1_kernel<<<dim3(32, 4, NE), 256, 0, stream>>>(
        xq, xs, rsrc, counts, wt1, gus, gub, smo, actb);
    requant_kernel<<<dim3(NE * CAP), 256, 0, stream>>>(actb, counts, hq, hsb);
    gemm2_kernel<<<dim3(16, 4, NE), 256, 0, stream>>>(
        hq, hsb, rsrc, rw, counts, wt2, dsc, dbi, out);
}